// Round 3
// baseline (263.855 us; speedup 1.0000x reference)
//
#include <hip/hip_runtime.h>

#define D_DIM 128
#define N_DIM 8192
#define B_DIM 32
#define BK 64
#define KSPL 32

typedef float f32x4 __attribute__((ext_vector_type(4)));
typedef short bf16x8 __attribute__((ext_vector_type(8)));
typedef unsigned short u16;

__device__ __forceinline__ u16 f2bf(float f) {
    unsigned int u = __builtin_bit_cast(unsigned int, f);
    u += 0x7FFFu + ((u >> 16) & 1u);   // round-to-nearest-even
    return (u16)(u >> 16);
}

// Kernel 1: per (kslice, batch) block, compute partial X^T X (128x128) over
// kc rows, plus partial column sums. LDS layout: bf16 [d=128][k=64] with
// XOR swizzle on 16B granules: element (d,k) at d*64 + (((k>>3)^(d&7))*8) + (k&7).
// Partial products are dumped in raw MFMA-fragment order (coalesced float4);
// cov_reduce decodes the layout.
// __launch_bounds__(256,4): 4 waves/EU -> 4 blocks/CU resident (VGPR<=128).
__global__ __launch_bounds__(256, 4) void cov_partial(
    const float* __restrict__ in, float* __restrict__ ws_p,
    float* __restrict__ ws_s, int kc) {
    __shared__ u16 lds[D_DIM * BK];     // 16 KB
    __shared__ float red[8][D_DIM];     // 4 KB

    const int t    = threadIdx.x;
    const int b    = blockIdx.y;
    const int ks   = blockIdx.x;
    const int dc   = t >> 3;            // 0..31: d-quad (cols of X)
    const int nr   = t & 7;             // 0..7 : n-quad within 32-row half
    const int wv   = t >> 6;            // wave 0..3
    const int lane = t & 63;
    const int m    = lane & 15;
    const int q    = lane >> 4;

    const int nstep = kc / BK;
    const float* src = in + (size_t)b * (N_DIM * D_DIM) + (size_t)ks * kc * D_DIM;

    f32x4 acc[2][8];
#pragma unroll
    for (int r = 0; r < 2; ++r)
#pragma unroll
        for (int c = 0; c < 8; ++c) acc[r][c] = (f32x4)0.0f;

    float sum4[4] = {0.f, 0.f, 0.f, 0.f};

    // buf[sub*4+i] = float4 of row (sub*32 + 4*nr + i), cols 4*dc..4*dc+3
    f32x4 buf[8];
    {
        const float* p = src;
#pragma unroll
        for (int sub = 0; sub < 2; ++sub)
#pragma unroll
            for (int i = 0; i < 4; ++i)
                buf[sub * 4 + i] =
                    *(const f32x4*)(p + (size_t)(sub * 32 + 4 * nr + i) * D_DIM + 4 * dc);
    }

    for (int s = 0; s < nstep; ++s) {
        // column sums (fp32, before conversion)
#pragma unroll
        for (int x = 0; x < 8; ++x)
#pragma unroll
            for (int j = 0; j < 4; ++j) sum4[j] += buf[x][j];

        // in-register 4x4 transpose + fp32->bf16
        ushort4 wvreg[2][4];
#pragma unroll
        for (int sub = 0; sub < 2; ++sub)
#pragma unroll
            for (int j = 0; j < 4; ++j) {
                wvreg[sub][j].x = f2bf(buf[sub * 4 + 0][j]);
                wvreg[sub][j].y = f2bf(buf[sub * 4 + 1][j]);
                wvreg[sub][j].z = f2bf(buf[sub * 4 + 2][j]);
                wvreg[sub][j].w = f2bf(buf[sub * 4 + 3][j]);
            }

        // prefetch next k-step (buf now free)
        if (s + 1 < nstep) {
            const float* p = src + (size_t)(s + 1) * BK * D_DIM;
#pragma unroll
            for (int sub = 0; sub < 2; ++sub)
#pragma unroll
                for (int i = 0; i < 4; ++i)
                    buf[sub * 4 + i] =
                        *(const f32x4*)(p + (size_t)(sub * 32 + 4 * nr + i) * D_DIM + 4 * dc);
        }

        __syncthreads();  // all waves done reading previous tile
#pragma unroll
        for (int sub = 0; sub < 2; ++sub)
#pragma unroll
            for (int j = 0; j < 4; ++j) {
                int d = 4 * dc + j;
                int g = sub * 4 + (nr >> 1);            // 16B granule index (k/8)
                int slot = g ^ (d & 7);                 // swizzle
                int off = d * 64 + slot * 8 + 4 * (nr & 1);
                *(ushort4*)(lds + off) = wvreg[sub][j]; // ds_write_b64
            }
        __syncthreads();

        // MFMA: C = X^T X. Column fragments Fcol[0..7] (constant indices) and
        // this wave's two row fragments Frow[0..1] (runtime wv folded into the
        // ADDRESS, never the array index — dynamic local-array indexing
        // demotes to scratch).
#pragma unroll
        for (int h = 0; h < 2; ++h) {
            bf16x8 Fcol[8];
#pragma unroll
            for (int tt = 0; tt < 8; ++tt) {
                int slot = (4 * h + q) ^ (m & 7);
                Fcol[tt] = *(const bf16x8*)(lds + (16 * tt + m) * 64 + slot * 8);
            }
            bf16x8 Frow[2];
#pragma unroll
            for (int r = 0; r < 2; ++r) {
                int row = 32 * wv + 16 * r + m;
                int slot = (4 * h + q) ^ (m & 7);
                Frow[r] = *(const bf16x8*)(lds + row * 64 + slot * 8);
            }
#pragma unroll
            for (int r = 0; r < 2; ++r)
#pragma unroll
                for (int c = 0; c < 8; ++c)
                    acc[r][c] = __builtin_amdgcn_mfma_f32_16x16x32_bf16(
                        Frow[r], Fcol[c], acc[r][c], 0, 0, 0);
        }
    }

    // reduce column sums across the 8 n-quads
#pragma unroll
    for (int j = 0; j < 4; ++j) red[nr][4 * dc + j] = sum4[j];
    __syncthreads();
    if (t < D_DIM) {
        float ssum = 0.f;
#pragma unroll
        for (int i = 0; i < 8; ++i) ssum += red[i][t];
        ws_s[(size_t)(b * gridDim.x + ks) * D_DIM + t] = ssum;
    }

    // Dump partial product in RAW fragment order — fully coalesced float4
    // stores. Flat offset (in floats): t*64 + (r*8+c)*4 + i.
    f32x4* outv = (f32x4*)(ws_p + (size_t)(b * gridDim.x + ks) * (D_DIM * D_DIM));
#pragma unroll
    for (int r = 0; r < 2; ++r)
#pragma unroll
        for (int c = 0; c < 8; ++c)
            outv[t * 16 + r * 8 + c] = acc[r][c];
}

// Kernel 2: sum partials (float4), decode fragment layout, subtract mean
// outer product, write cov. Grid: (B_DIM * 16) blocks x 256 threads; each
// thread owns one float4 of the 16384-float partial chunk.
__global__ __launch_bounds__(256) void cov_reduce(
    const float* __restrict__ ws_p, const float* __restrict__ ws_s,
    float* __restrict__ out, int kspl) {
    int b = blockIdx.x >> 4;
    int chunk = blockIdx.x & 15;
    int g = chunk * 256 + threadIdx.x;   // float4 index, 0..4095

    __shared__ float mean[D_DIM];
    if (threadIdx.x < D_DIM) {
        float s = 0.f;
        for (int ks = 0; ks < kspl; ++ks)
            s += ws_s[(size_t)(b * kspl + ks) * D_DIM + threadIdx.x];
        mean[threadIdx.x] = s * (1.0f / (float)N_DIM);
    }
    __syncthreads();

    const f32x4* pv = (const f32x4*)ws_p;
    f32x4 acc = (f32x4)0.0f;
    for (int ks = 0; ks < kspl; ++ks) {
        f32x4 v = pv[(size_t)(b * kspl + ks) * (D_DIM * D_DIM / 4) + g];
        acc.x += v.x; acc.y += v.y; acc.z += v.z; acc.w += v.w;
    }

    // decode: flat float index f = 4*g + i = t2*64 + (r*8+c)*4 + i
    int t2 = g >> 4;
    int rc = g & 15;
    int r = rc >> 3, c = rc & 7;
    int wv = t2 >> 6;
    int lane = t2 & 63;
    int m = lane & 15;
    int q = lane >> 4;
    int d0 = 32 * wv + 16 * r + 4 * q;
    int e = 16 * c + m;

    const float invN = 1.0f / (float)N_DIM;
    float me = mean[e];
    float* ob = out + (size_t)b * (D_DIM * D_DIM);
#pragma unroll
    for (int i = 0; i < 4; ++i) {
        int d = d0 + i;
        ob[(size_t)d * D_DIM + e] = acc[i] * invN - mean[d] * me;
    }
}

extern "C" void kernel_launch(void* const* d_in, const int* in_sizes, int n_in,
                              void* d_out, int out_size, void* d_ws, size_t ws_size,
                              hipStream_t stream) {
    const float* in = (const float*)d_in[0];
    float* out = (float*)d_out;

    // pick largest K-split whose partials fit the workspace
    int kspl = KSPL;
    while (kspl > 1 &&
           (size_t)kspl * B_DIM * (size_t)(D_DIM * D_DIM + D_DIM) * sizeof(float) > ws_size)
        kspl >>= 1;
    int kc = N_DIM / kspl;

    float* ws_p = (float*)d_ws;
    float* ws_s = ws_p + (size_t)kspl * B_DIM * (D_DIM * D_DIM);

    cov_partial<<<dim3(kspl, B_DIM), 256, 0, stream>>>(in, ws_p, ws_s, kc);
    cov_reduce<<<dim3(B_DIM * 16), 256, 0, stream>>>(ws_p, ws_s, out, kspl);
}

// Round 4
// 228.016 us; speedup vs baseline: 1.1572x; 1.1572x over previous
//
#include <hip/hip_runtime.h>

#define D_DIM 128
#define N_DIM 8192
#define B_DIM 32
#define BK 64
#define KSPL 32

typedef float f32x4 __attribute__((ext_vector_type(4)));
typedef short bf16x8 __attribute__((ext_vector_type(8)));
typedef unsigned short u16;

__device__ __forceinline__ u16 f2bf(float f) {
    unsigned int u = __builtin_bit_cast(unsigned int, f);
    u += 0x7FFFu + ((u >> 16) & 1u);   // round-to-nearest-even
    return (u16)(u >> 16);
}

// Kernel 1: per (kslice, batch) block, compute partial X^T X (128x128) over
// kc rows, plus partial column sums. LDS layout: bf16 [d=128][k=64] with
// XOR swizzle on 16B granules: element (d,k) at d*64 + (((k>>3)^(d&7))*8) + (k&7).
// Partial products are dumped in raw MFMA-fragment order (coalesced float4);
// cov_reduce decodes the layout.
//
// __launch_bounds__(256, 2): do NOT raise the min-waves arg — (256,4) forced
// VGPR 108->64 and spilled ~142 MB of scratch per dispatch (round-3 counters).
// At VGPR=108 the HW already fits 4 waves/EU (432<=512), so 4 blocks/CU comes
// from the grid (KSPL=32 -> 1024 blocks), not from the allocator.
__global__ __launch_bounds__(256, 2) void cov_partial(
    const float* __restrict__ in, float* __restrict__ ws_p,
    float* __restrict__ ws_s, int kc) {
    __shared__ u16 lds[D_DIM * BK];     // 16 KB
    __shared__ float red[8][D_DIM];     // 4 KB

    const int t    = threadIdx.x;
    const int b    = blockIdx.y;
    const int ks   = blockIdx.x;
    const int dc   = t >> 3;            // 0..31: d-quad (cols of X)
    const int nr   = t & 7;             // 0..7 : n-quad within 32-row half
    const int wv   = t >> 6;            // wave 0..3
    const int lane = t & 63;
    const int m    = lane & 15;
    const int q    = lane >> 4;

    const int nstep = kc / BK;
    const float* src = in + (size_t)b * (N_DIM * D_DIM) + (size_t)ks * kc * D_DIM;

    f32x4 acc[2][8];
#pragma unroll
    for (int r = 0; r < 2; ++r)
#pragma unroll
        for (int c = 0; c < 8; ++c) acc[r][c] = (f32x4)0.0f;

    float sum4[4] = {0.f, 0.f, 0.f, 0.f};

    // buf[sub*4+i] = float4 of row (sub*32 + 4*nr + i), cols 4*dc..4*dc+3
    f32x4 buf[8];
    {
        const float* p = src;
#pragma unroll
        for (int sub = 0; sub < 2; ++sub)
#pragma unroll
            for (int i = 0; i < 4; ++i)
                buf[sub * 4 + i] =
                    *(const f32x4*)(p + (size_t)(sub * 32 + 4 * nr + i) * D_DIM + 4 * dc);
    }

    for (int s = 0; s < nstep; ++s) {
        // column sums (fp32, before conversion)
#pragma unroll
        for (int x = 0; x < 8; ++x)
#pragma unroll
            for (int j = 0; j < 4; ++j) sum4[j] += buf[x][j];

        // in-register 4x4 transpose + fp32->bf16
        ushort4 wvreg[2][4];
#pragma unroll
        for (int sub = 0; sub < 2; ++sub)
#pragma unroll
            for (int j = 0; j < 4; ++j) {
                wvreg[sub][j].x = f2bf(buf[sub * 4 + 0][j]);
                wvreg[sub][j].y = f2bf(buf[sub * 4 + 1][j]);
                wvreg[sub][j].z = f2bf(buf[sub * 4 + 2][j]);
                wvreg[sub][j].w = f2bf(buf[sub * 4 + 3][j]);
            }

        // prefetch next k-step (buf now free)
        if (s + 1 < nstep) {
            const float* p = src + (size_t)(s + 1) * BK * D_DIM;
#pragma unroll
            for (int sub = 0; sub < 2; ++sub)
#pragma unroll
                for (int i = 0; i < 4; ++i)
                    buf[sub * 4 + i] =
                        *(const f32x4*)(p + (size_t)(sub * 32 + 4 * nr + i) * D_DIM + 4 * dc);
        }

        __syncthreads();  // all waves done reading previous tile
#pragma unroll
        for (int sub = 0; sub < 2; ++sub)
#pragma unroll
            for (int j = 0; j < 4; ++j) {
                int d = 4 * dc + j;
                int g = sub * 4 + (nr >> 1);            // 16B granule index (k/8)
                int slot = g ^ (d & 7);                 // swizzle
                int off = d * 64 + slot * 8 + 4 * (nr & 1);
                *(ushort4*)(lds + off) = wvreg[sub][j]; // ds_write_b64
            }
        __syncthreads();

        // MFMA: C = X^T X. Column fragments Fcol[0..7] (constant indices) and
        // this wave's two row fragments Frow[0..1] (runtime wv folded into the
        // ADDRESS, never the array index — dynamic local-array indexing
        // demotes to scratch).
#pragma unroll
        for (int h = 0; h < 2; ++h) {
            bf16x8 Fcol[8];
#pragma unroll
            for (int tt = 0; tt < 8; ++tt) {
                int slot = (4 * h + q) ^ (m & 7);
                Fcol[tt] = *(const bf16x8*)(lds + (16 * tt + m) * 64 + slot * 8);
            }
            bf16x8 Frow[2];
#pragma unroll
            for (int r = 0; r < 2; ++r) {
                int row = 32 * wv + 16 * r + m;
                int slot = (4 * h + q) ^ (m & 7);
                Frow[r] = *(const bf16x8*)(lds + row * 64 + slot * 8);
            }
#pragma unroll
            for (int r = 0; r < 2; ++r)
#pragma unroll
                for (int c = 0; c < 8; ++c)
                    acc[r][c] = __builtin_amdgcn_mfma_f32_16x16x32_bf16(
                        Frow[r], Fcol[c], acc[r][c], 0, 0, 0);
        }
    }

    // reduce column sums across the 8 n-quads
#pragma unroll
    for (int j = 0; j < 4; ++j) red[nr][4 * dc + j] = sum4[j];
    __syncthreads();
    if (t < D_DIM) {
        float ssum = 0.f;
#pragma unroll
        for (int i = 0; i < 8; ++i) ssum += red[i][t];
        ws_s[(size_t)(b * gridDim.x + ks) * D_DIM + t] = ssum;
    }

    // Dump partial product in RAW fragment order — fully coalesced float4
    // stores. Flat offset (in floats): t*64 + (r*8+c)*4 + i.
    f32x4* outv = (f32x4*)(ws_p + (size_t)(b * gridDim.x + ks) * (D_DIM * D_DIM));
#pragma unroll
    for (int r = 0; r < 2; ++r)
#pragma unroll
        for (int c = 0; c < 8; ++c)
            outv[t * 16 + r * 8 + c] = acc[r][c];
}

// Kernel 2: sum partials (float4), decode fragment layout, subtract mean
// outer product, write cov. Grid: (B_DIM * 16) blocks x 256 threads; each
// thread owns one float4 of the 16384-float partial chunk.
__global__ __launch_bounds__(256) void cov_reduce(
    const float* __restrict__ ws_p, const float* __restrict__ ws_s,
    float* __restrict__ out, int kspl) {
    int b = blockIdx.x >> 4;
    int chunk = blockIdx.x & 15;
    int g = chunk * 256 + threadIdx.x;   // float4 index, 0..4095

    __shared__ float mean[D_DIM];
    if (threadIdx.x < D_DIM) {
        float s = 0.f;
        for (int ks = 0; ks < kspl; ++ks)
            s += ws_s[(size_t)(b * kspl + ks) * D_DIM + threadIdx.x];
        mean[threadIdx.x] = s * (1.0f / (float)N_DIM);
    }
    __syncthreads();

    const f32x4* pv = (const f32x4*)ws_p;
    f32x4 acc = (f32x4)0.0f;
    for (int ks = 0; ks < kspl; ++ks) {
        f32x4 v = pv[(size_t)(b * kspl + ks) * (D_DIM * D_DIM / 4) + g];
        acc.x += v.x; acc.y += v.y; acc.z += v.z; acc.w += v.w;
    }

    // decode: flat float index f = 4*g + i = t2*64 + (r*8+c)*4 + i
    int t2 = g >> 4;
    int rc = g & 15;
    int r = rc >> 3, c = rc & 7;
    int wv = t2 >> 6;
    int lane = t2 & 63;
    int m = lane & 15;
    int q = lane >> 4;
    int d0 = 32 * wv + 16 * r + 4 * q;
    int e = 16 * c + m;

    const float invN = 1.0f / (float)N_DIM;
    float me = mean[e];
    float* ob = out + (size_t)b * (D_DIM * D_DIM);
#pragma unroll
    for (int i = 0; i < 4; ++i) {
        int d = d0 + i;
        ob[(size_t)d * D_DIM + e] = acc[i] * invN - mean[d] * me;
    }
}

extern "C" void kernel_launch(void* const* d_in, const int* in_sizes, int n_in,
                              void* d_out, int out_size, void* d_ws, size_t ws_size,
                              hipStream_t stream) {
    const float* in = (const float*)d_in[0];
    float* out = (float*)d_out;

    // pick largest K-split whose partials fit the workspace
    int kspl = KSPL;
    while (kspl > 1 &&
           (size_t)kspl * B_DIM * (size_t)(D_DIM * D_DIM + D_DIM) * sizeof(float) > ws_size)
        kspl >>= 1;
    int kc = N_DIM / kspl;

    float* ws_p = (float*)d_ws;
    float* ws_s = ws_p + (size_t)kspl * B_DIM * (D_DIM * D_DIM);

    cov_partial<<<dim3(kspl, B_DIM), 256, 0, stream>>>(in, ws_p, ws_s, kc);
    cov_reduce<<<dim3(B_DIM * 16), 256, 0, stream>>>(ws_p, ws_s, out, kspl);
}

// Round 5
// 208.625 us; speedup vs baseline: 1.2647x; 1.0929x over previous
//
#include <hip/hip_runtime.h>

#define D_DIM 128
#define N_DIM 8192
#define B_DIM 32
#define KSPL 16
#define KC   512     // N_DIM / KSPL rows per block
#define BK   256     // k-rows per LDS fill (one barrier PAIR per BK rows)

typedef float f32x4 __attribute__((ext_vector_type(4)));
typedef short bf16x8 __attribute__((ext_vector_type(8)));
typedef unsigned short u16;

__device__ __forceinline__ u16 f2bf(float f) {
    unsigned int u = __builtin_bit_cast(unsigned int, f);
    u += 0x7FFFu + ((u >> 16) & 1u);   // round-to-nearest-even
    return (u16)(u >> 16);
}

// Load one 64-row chunk: thread (dc,nr) takes rows gc*64 + sub*32 + 4*nr + i,
// cols 4*dc..4*dc+3.
__device__ __forceinline__ void load_chunk(f32x4 (&buf)[8], const float* src,
                                           int gc, int nr, int dc) {
    const float* p = src + (size_t)gc * 64 * D_DIM;
#pragma unroll
    for (int sub = 0; sub < 2; ++sub)
#pragma unroll
        for (int i = 0; i < 4; ++i)
            buf[sub * 4 + i] =
                *(const f32x4*)(p + (size_t)(sub * 32 + 4 * nr + i) * D_DIM + 4 * dc);
}

// Column sums + fp32->bf16 + swizzled LDS write (NO barrier — chunks of one
// BK-fill pipeline freely; each wave writes disjoint rows).
// LDS layout: (d,k) at d*256 + (( (k>>3) ^ (d&7) )*8) + (k&7), k = local 0..255.
__device__ __forceinline__ void proc_write(u16* lds, f32x4 (&buf)[8],
                                           float (&sum4)[4], int gc, int nr, int dc) {
#pragma unroll
    for (int x = 0; x < 8; ++x)
#pragma unroll
        for (int j = 0; j < 4; ++j) sum4[j] += buf[x][j];
#pragma unroll
    for (int sub = 0; sub < 2; ++sub)
#pragma unroll
        for (int j = 0; j < 4; ++j) {
            ushort4 w;
            w.x = f2bf(buf[sub * 4 + 0][j]);
            w.y = f2bf(buf[sub * 4 + 1][j]);
            w.z = f2bf(buf[sub * 4 + 2][j]);
            w.w = f2bf(buf[sub * 4 + 3][j]);
            int d = 4 * dc + j;
            int g = (gc & 3) * 8 + sub * 4 + (nr >> 1);  // 16B granule of local k
            int slot = g ^ (d & 7);
            *(ushort4*)(lds + d * 256 + slot * 8 + 4 * (nr & 1)) = w;
        }
}

// MFMA over the full 256-k LDS buffer. Runtime wv only ever in ADDRESSES.
__device__ __forceinline__ void mfma_phase(const u16* lds, f32x4 (&acc)[2][8],
                                           int wv, int m, int q) {
#pragma unroll
    for (int h = 0; h < 8; ++h) {
        int slotbase = h * 4 + q;
        bf16x8 Fcol[8];
#pragma unroll
        for (int tt = 0; tt < 8; ++tt) {
            int slot = slotbase ^ (m & 7);
            Fcol[tt] = *(const bf16x8*)(lds + (16 * tt + m) * 256 + slot * 8);
        }
        bf16x8 Frow0, Frow1;
        {
            int slot = slotbase ^ (m & 7);
            Frow0 = *(const bf16x8*)(lds + (32 * wv + m) * 256 + slot * 8);
            Frow1 = *(const bf16x8*)(lds + (32 * wv + 16 + m) * 256 + slot * 8);
        }
#pragma unroll
        for (int c = 0; c < 8; ++c)
            acc[0][c] = __builtin_amdgcn_mfma_f32_16x16x32_bf16(Frow0, Fcol[c],
                                                                acc[0][c], 0, 0, 0);
#pragma unroll
        for (int c = 0; c < 8; ++c)
            acc[1][c] = __builtin_amdgcn_mfma_f32_16x16x32_bf16(Frow1, Fcol[c],
                                                                acc[1][c], 0, 0, 0);
    }
}

// __launch_bounds__(256,2): (256,4) forced VGPR->64 and spilled 142 MB (R3).
// LDS 68 KB -> 2 blocks/CU; KSPL=16 -> 512 blocks = exactly 2/CU.
__global__ __launch_bounds__(256, 2) void cov_partial(
    const float* __restrict__ in, float* __restrict__ ws_p,
    float* __restrict__ ws_s) {
    __shared__ u16 lds[D_DIM * BK];     // 64 KB
    __shared__ float red[8][D_DIM];     // 4 KB

    const int t    = threadIdx.x;
    const int b    = blockIdx.y;
    const int ks   = blockIdx.x;
    const int dc   = t >> 3;
    const int nr   = t & 7;
    const int wv   = t >> 6;
    const int lane = t & 63;
    const int m    = lane & 15;
    const int q    = lane >> 4;

    const float* src = in + (size_t)b * (N_DIM * D_DIM) + (size_t)ks * KC * D_DIM;

    f32x4 acc[2][8];
#pragma unroll
    for (int r = 0; r < 2; ++r)
#pragma unroll
        for (int c = 0; c < 8; ++c) acc[r][c] = (f32x4)0.0f;
    float sum4[4] = {0.f, 0.f, 0.f, 0.f};

    f32x4 bufA[8], bufB[8];

    // ---- step 0: fill LDS with k=0..255, barrier-free chunk pipeline ----
    load_chunk(bufA, src, 0, nr, dc);
    load_chunk(bufB, src, 1, nr, dc);
    proc_write(lds, bufA, sum4, 0, nr, dc);
    load_chunk(bufA, src, 2, nr, dc);
    proc_write(lds, bufB, sum4, 1, nr, dc);
    load_chunk(bufB, src, 3, nr, dc);
    proc_write(lds, bufA, sum4, 2, nr, dc);
    load_chunk(bufA, src, 4, nr, dc);       // next step's chunk 0 — in flight early
    proc_write(lds, bufB, sum4, 3, nr, dc);
    __syncthreads();
    mfma_phase(lds, acc, wv, m, q);
    __syncthreads();

    // ---- step 1: k=256..511 ----
    load_chunk(bufB, src, 5, nr, dc);
    proc_write(lds, bufA, sum4, 4, nr, dc);
    load_chunk(bufA, src, 6, nr, dc);
    proc_write(lds, bufB, sum4, 5, nr, dc);
    load_chunk(bufB, src, 7, nr, dc);
    proc_write(lds, bufA, sum4, 6, nr, dc);
    proc_write(lds, bufB, sum4, 7, nr, dc);
    __syncthreads();
    mfma_phase(lds, acc, wv, m, q);

    // ---- column-sum reduction across the 8 n-octets ----
    __syncthreads();
#pragma unroll
    for (int j = 0; j < 4; ++j) red[nr][4 * dc + j] = sum4[j];
    __syncthreads();
    if (t < D_DIM) {
        float ssum = 0.f;
#pragma unroll
        for (int i = 0; i < 8; ++i) ssum += red[i][t];
        ws_s[(size_t)(b * KSPL + ks) * D_DIM + t] = ssum;
    }

    // ---- dump partial product in RAW fragment order (coalesced float4) ----
    f32x4* outv = (f32x4*)(ws_p + (size_t)(b * KSPL + ks) * (D_DIM * D_DIM));
#pragma unroll
    for (int r = 0; r < 2; ++r)
#pragma unroll
        for (int c = 0; c < 8; ++c)
            outv[t * 16 + r * 8 + c] = acc[r][c];
}

// Kernel 2: sum partials (float4), decode fragment layout, subtract mean
// outer product, write cov.
__global__ __launch_bounds__(256) void cov_reduce(
    const float* __restrict__ ws_p, const float* __restrict__ ws_s,
    float* __restrict__ out, int kspl) {
    int b = blockIdx.x >> 4;
    int chunk = blockIdx.x & 15;
    int g = chunk * 256 + threadIdx.x;   // float4 index, 0..4095

    __shared__ float mean[D_DIM];
    if (threadIdx.x < D_DIM) {
        float s = 0.f;
        for (int ks = 0; ks < kspl; ++ks)
            s += ws_s[(size_t)(b * kspl + ks) * D_DIM + threadIdx.x];
        mean[threadIdx.x] = s * (1.0f / (float)N_DIM);
    }
    __syncthreads();

    const f32x4* pv = (const f32x4*)ws_p;
    f32x4 acc = (f32x4)0.0f;
    for (int ks = 0; ks < kspl; ++ks) {
        f32x4 v = pv[(size_t)(b * kspl + ks) * (D_DIM * D_DIM / 4) + g];
        acc.x += v.x; acc.y += v.y; acc.z += v.z; acc.w += v.w;
    }

    // decode: flat float index f = 4*g + i = t2*64 + (r*8+c)*4 + i
    int t2 = g >> 4;
    int rc = g & 15;
    int r = rc >> 3, c = rc & 7;
    int wv = t2 >> 6;
    int lane = t2 & 63;
    int m = lane & 15;
    int q = lane >> 4;
    int d0 = 32 * wv + 16 * r + 4 * q;
    int e = 16 * c + m;

    const float invN = 1.0f / (float)N_DIM;
    float me = mean[e];
    float* ob = out + (size_t)b * (D_DIM * D_DIM);
#pragma unroll
    for (int i = 0; i < 4; ++i) {
        int d = d0 + i;
        ob[(size_t)d * D_DIM + e] = acc[i] * invN - mean[d] * me;
    }
}

extern "C" void kernel_launch(void* const* d_in, const int* in_sizes, int n_in,
                              void* d_out, int out_size, void* d_ws, size_t ws_size,
                              hipStream_t stream) {
    const float* in = (const float*)d_in[0];
    float* out = (float*)d_out;

    float* ws_p = (float*)d_ws;
    float* ws_s = ws_p + (size_t)KSPL * B_DIM * (D_DIM * D_DIM);

    cov_partial<<<dim3(KSPL, B_DIM), 256, 0, stream>>>(in, ws_p, ws_s);
    cov_reduce<<<dim3(B_DIM * 16), 256, 0, stream>>>(ws_p, ws_s, out, KSPL);
}